// Round 3
// baseline (135.174 us; speedup 1.0000x reference)
//
#include <hip/hip_runtime.h>
#include <math.h>

#define H 4
#define HD 64
#define NN 1024
#define BB 8
#define FIN 256
#define FOUT 256

typedef _Float16 f16x8 __attribute__((ext_vector_type(8)));
typedef _Float16 f16x4 __attribute__((ext_vector_type(4)));
typedef _Float16 f16x2 __attribute__((ext_vector_type(2)));
typedef float f32x4 __attribute__((ext_vector_type(4)));

// ---------------------------------------------------------------------------
// Kernel 0: WT[f][k] = (fp16) W[k][f] in 64x64 tiles. 16 blocks.
// ---------------------------------------------------------------------------
__global__ __launch_bounds__(256) void prep_w(const float* __restrict__ W,
                                              _Float16* __restrict__ WT) {
  __shared__ float tile[64][68];
  const int tid = threadIdx.x;
  const int bx = blockIdx.x;
  const int k0 = (bx & 3) * 64, f0 = (bx >> 2) * 64;
  const int r = tid >> 4, c4 = (tid & 15) * 4;
#pragma unroll
  for (int p = 0; p < 4; ++p) {
    float4 v = *(const float4*)&W[(size_t)(k0 + p * 16 + r) * FOUT + f0 + c4];
    *(float4*)&tile[p * 16 + r][c4] = v;
  }
  __syncthreads();
  const int f = tid >> 2, kg = (tid & 3) * 16;
#pragma unroll
  for (int i = 0; i < 4; ++i) {
    f16x4 o;
#pragma unroll
    for (int j = 0; j < 4; ++j) o[j] = (_Float16)tile[kg + i * 4 + j][f];
    *(f16x4*)&WT[(size_t)(f0 + f) * FIN + k0 + kg + i * 4] = o;
  }
}

// ---------------------------------------------------------------------------
// Kernel 1: fused. blockIdx.x < 128: h = x @ W via fp16 MFMA (64 rows x head).
// blockIdx.x >= 128: adj bit-pack (overlaps the 32 MB adj stream with GEMM).
// GEMM epilogue fuses scores s1, s2.
// ---------------------------------------------------------------------------
__global__ __launch_bounds__(256) void gemm_pack(const float* __restrict__ x,
                                                 const _Float16* __restrict__ WT,
                                                 const float* __restrict__ a,
                                                 const int* __restrict__ adj,
                                                 unsigned* __restrict__ adjP,
                                                 _Float16* __restrict__ hT,
                                                 float* __restrict__ s1_ws,
                                                 float* __restrict__ s2_ws) {
  __shared__ _Float16 xs[64][264];  // stride 528B
  const int tid = threadIdx.x;

  if (blockIdx.x >= 128) {  // ---- adj pack path ----
    const int p = (blockIdx.x - 128) + 256 * blockIdx.y;  // 0..1023
    size_t widx = (size_t)p * 256 + tid;                  // [0, 8*1024*32)
    const int4* ap = (const int4*)adj + widx * 8;
    int4 v[8];
#pragma unroll
    for (int i = 0; i < 8; ++i) v[i] = ap[i];
    unsigned bits = 0;
#pragma unroll
    for (int i = 0; i < 8; ++i) {
      bits |= (v[i].x != 0 ? 1u : 0u) << (4 * i);
      bits |= (v[i].y != 0 ? 2u : 0u) << (4 * i);
      bits |= (v[i].z != 0 ? 4u : 0u) << (4 * i);
      bits |= (v[i].w != 0 ? 8u : 0u) << (4 * i);
    }
    adjP[widx] = bits;
    return;
  }

  // ---- GEMM path ----
  const int lane = tid & 63, w = tid >> 6;
  const int c = lane & 15, q = lane >> 4;
  const int bn0 = blockIdx.x * 64;
  const int head = blockIdx.y;
  const int b = bn0 >> 10, nb = bn0 & 1023;
  const int bh = b * H + head;

  float4 v[16];
#pragma unroll
  for (int p = 0; p < 16; ++p) {
    int f = p * 256 + tid;  // float4 index in [0, 4096)
    int row = f >> 6, col = (f & 63) * 4;
    v[p] = *(const float4*)&x[(size_t)(bn0 + row) * FIN + col];
  }
#pragma unroll
  for (int p = 0; p < 16; ++p) {
    int f = p * 256 + tid;
    int row = f >> 6, col = (f & 63) * 4;
    f16x4 h4;
    h4[0] = (_Float16)v[p].x; h4[1] = (_Float16)v[p].y;
    h4[2] = (_Float16)v[p].z; h4[3] = (_Float16)v[p].w;
    *(f16x4*)&xs[row][col] = h4;
  }
  __syncthreads();

  f32x4 acc[4];
#pragma unroll
  for (int t = 0; t < 4; ++t) acc[t] = (f32x4){0.f, 0.f, 0.f, 0.f};
  const _Float16* wbase = WT + (size_t)head * 64 * FIN;
#pragma unroll
  for (int ks = 0; ks < 8; ++ks) {
    f16x8 af = *(const f16x8*)&xs[w * 16 + c][ks * 32 + q * 8];
#pragma unroll
    for (int t = 0; t < 4; ++t) {
      f16x8 bf = *(const f16x8*)&wbase[(size_t)(t * 16 + c) * FIN + ks * 32 + q * 8];
      acc[t] = __builtin_amdgcn_mfma_f32_16x16x32_f16(af, bf, acc[t], 0, 0, 0);
    }
  }

  float a1v[4], a2v[4];
#pragma unroll
  for (int t = 0; t < 4; ++t) {
    a1v[t] = a[head * 2 * HD + t * 16 + c];
    a2v[t] = a[head * 2 * HD + HD + t * 16 + c];
  }
  float s1p[4] = {0.f, 0.f, 0.f, 0.f};
  float s2p[4] = {0.f, 0.f, 0.f, 0.f};
#pragma unroll
  for (int t = 0; t < 4; ++t) {
    f16x4 hv;
#pragma unroll
    for (int rr = 0; rr < 4; ++rr) {
      hv[rr] = (_Float16)acc[t][rr];
      s1p[rr] += acc[t][rr] * a1v[t];
      s2p[rr] += acc[t][rr] * a2v[t];
    }
    *(f16x4*)&hT[((size_t)(bh * 64 + t * 16 + c)) * NN + nb + w * 16 + q * 4] = hv;
  }
#pragma unroll
  for (int rr = 0; rr < 4; ++rr) {
    float s1 = s1p[rr], s2 = s2p[rr];
#pragma unroll
    for (int off = 8; off; off >>= 1) {
      s1 += __shfl_xor(s1, off);
      s2 += __shfl_xor(s2, off);
    }
    if (c == 0) {
      int n = nb + w * 16 + q * 4 + rr;
      size_t idx = (size_t)bh * NN + n;
      s1_ws[idx] = s1;
      s2_ws[idx] = s2;
    }
  }
}

// ---------------------------------------------------------------------------
// Kernel 2: attention, barrier-free main loop. Block = 16 n-rows x (b,h);
// grid 64x32. Wave w owns (dblock = w>>1 [32 dims], khalf = w&1 [512 m]).
// Each lane builds its MFMA A-fragment (row c, m = K0+kb*32+q*8..+7) directly
// in registers: mask byte from transposed adjW, s2/u/v broadcast LDS reads.
// No pt LDS tile, no per-chunk barriers; 2 independent acc chains per wave.
// 3 block barriers total (stage, row-max exchange, L/acc exchange).
// ---------------------------------------------------------------------------
__global__ __launch_bounds__(256) void attn(const _Float16* __restrict__ hT,
                                            const float* __restrict__ s1_ws,
                                            const float* __restrict__ s2_ws,
                                            const unsigned* __restrict__ adjP,
                                            float* __restrict__ out) {
  __shared__ float s2r[NN], uu[NN], vv[NN];  // 12 KB
  __shared__ unsigned adjW[32][16];          // 2 KB, transposed: [word][row]
  __shared__ float maxbuf[4][16];
  __shared__ float Lbuf[2][16];
  __shared__ float accbuf[2][64][8];         // 4 KB
  const int tid = threadIdx.x, lane = tid & 63, w = tid >> 6;
  const int c = lane & 15, q = lane >> 4;
  const int ntile = blockIdx.x, bh = blockIdx.y;
  const int b = bh >> 2, head = bh & 3;
  const int n0 = ntile * 16;
  const int dblock = w >> 1, khalf = w & 1;
  const int K0 = khalf * 512;

  {
    float4 s2f = *(const float4*)&s2_ws[(size_t)bh * NN + tid * 4];
    *(float4*)&s2r[tid * 4] = s2f;
    float4 u4 = make_float4(__expf(s2f.x), __expf(s2f.y), __expf(s2f.z), __expf(s2f.w));
    *(float4*)&uu[tid * 4] = u4;
    float4 v4 = make_float4(__expf(0.2f * s2f.x), __expf(0.2f * s2f.y),
                            __expf(0.2f * s2f.z), __expf(0.2f * s2f.w));
    *(float4*)&vv[tid * 4] = v4;
    if (tid < 128) {
      const int row = tid >> 3, wd0 = (tid & 7) * 4;
      uint4 aw = *(const uint4*)&adjP[((size_t)(b * NN + n0 + row)) * 32 + wd0];
      adjW[wd0 + 0][row] = aw.x;
      adjW[wd0 + 1][row] = aw.y;
      adjW[wd0 + 2][row] = aw.z;
      adjW[wd0 + 3][row] = aw.w;
    }
  }
  float s1v = s1_ws[(size_t)bh * NN + n0 + c];  // this lane's row constant
  __syncthreads();

  // ---- pass 1: masked row max of s2 over this wave's K-half ----
  float mx = -INFINITY;
#pragma unroll
  for (int kb = 0; kb < 16; ++kb) {
    int base = K0 + kb * 32 + q * 8;
    f32x4 sa = *(const f32x4*)&s2r[base];
    f32x4 sb = *(const f32x4*)&s2r[base + 4];
    unsigned bits = adjW[khalf * 16 + kb][c] >> (q * 8);
#pragma unroll
    for (int j = 0; j < 4; ++j) {
      mx = fmaxf(mx, ((bits >> j) & 1u) ? sa[j] : -INFINITY);
      mx = fmaxf(mx, ((bits >> (j + 4)) & 1u) ? sb[j] : -INFINITY);
    }
  }
  mx = fmaxf(mx, __shfl_xor(mx, 16));
  mx = fmaxf(mx, __shfl_xor(mx, 32));
  if (lane < 16) maxbuf[w][lane] = mx;
  __syncthreads();
  float mrow = fmaxf(fmaxf(maxbuf[0][c], maxbuf[1][c]),
                     fmaxf(maxbuf[2][c], maxbuf[3][c]));
  float t0 = s1v + mrow;
  float M = fmaxf(t0, 0.2f * t0);  // lrelu (monotone => exact row max)
  float Arow = __expf(s1v - M);
  float Brow = __expf(0.2f * s1v - M);
  float ns1 = -s1v;

  // ---- pass 2: barrier-free P-gen + MFMA over this wave's K-half ----
  float Lp = 0.f;
  f32x4 acc0 = (f32x4){0.f, 0.f, 0.f, 0.f};
  f32x4 acc1 = (f32x4){0.f, 0.f, 0.f, 0.f};
  const _Float16* bp0 = hT + ((size_t)bh * 64 + dblock * 32 + c) * NN + K0 + q * 8;
  const _Float16* bp1 = bp0 + (size_t)16 * NN;
#pragma unroll 4
  for (int kb = 0; kb < 16; ++kb) {
    int base = K0 + kb * 32 + q * 8;
    f32x4 sa = *(const f32x4*)&s2r[base];
    f32x4 sb = *(const f32x4*)&s2r[base + 4];
    f32x4 ua = *(const f32x4*)&uu[base];
    f32x4 ub = *(const f32x4*)&uu[base + 4];
    f32x4 va = *(const f32x4*)&vv[base];
    f32x4 vb = *(const f32x4*)&vv[base + 4];
    unsigned bits = adjW[khalf * 16 + kb][c] >> (q * 8);
    float p[8];
#pragma unroll
    for (int j = 0; j < 4; ++j) {
      float pa = (sa[j] >= ns1) ? Arow * ua[j] : Brow * va[j];
      float pb = (sb[j] >= ns1) ? Arow * ub[j] : Brow * vb[j];
      p[j] = ((bits >> j) & 1u) ? pa : 0.f;
      p[j + 4] = ((bits >> (j + 4)) & 1u) ? pb : 0.f;
    }
    Lp += ((p[0] + p[1]) + (p[2] + p[3])) + ((p[4] + p[5]) + (p[6] + p[7]));
    union { f16x8 v8; f16x2 h2[4]; } U;
    U.h2[0] = __builtin_bit_cast(f16x2, __builtin_amdgcn_cvt_pkrtz(p[0], p[1]));
    U.h2[1] = __builtin_bit_cast(f16x2, __builtin_amdgcn_cvt_pkrtz(p[2], p[3]));
    U.h2[2] = __builtin_bit_cast(f16x2, __builtin_amdgcn_cvt_pkrtz(p[4], p[5]));
    U.h2[3] = __builtin_bit_cast(f16x2, __builtin_amdgcn_cvt_pkrtz(p[6], p[7]));
    f16x8 bf0 = *(const f16x8*)(bp0 + kb * 32);
    f16x8 bf1 = *(const f16x8*)(bp1 + kb * 32);
    acc0 = __builtin_amdgcn_mfma_f32_16x16x32_f16(U.v8, bf0, acc0, 0, 0, 0);
    acc1 = __builtin_amdgcn_mfma_f32_16x16x32_f16(U.v8, bf1, acc1, 0, 0, 0);
  }

  // ---- epilogue: L reduce + cross-K-half acc reduce ----
  Lp += __shfl_xor(Lp, 16);
  Lp += __shfl_xor(Lp, 32);
  if (w < 2 && lane < 16) Lbuf[w][lane] = Lp;  // waves 2,3 duplicate 0,1
  if (khalf == 1) {
    *(f32x4*)&accbuf[dblock][lane][0] = acc0;
    *(f32x4*)&accbuf[dblock][lane][4] = acc1;
  }
  __syncthreads();
  if (khalf == 0) {
    f32x4 o0 = *(const f32x4*)&accbuf[dblock][lane][0];
    f32x4 o1 = *(const f32x4*)&accbuf[dblock][lane][4];
    acc0 += o0;
    acc1 += o1;
#pragma unroll
    for (int rr = 0; rr < 4; ++rr) {
      int row = q * 4 + rr;
      float il = 1.0f / (Lbuf[0][row] + Lbuf[1][row]);
      size_t o = ((size_t)(b * NN + n0 + row)) * FOUT + head * 64 + dblock * 32;
      out[o + c] = acc0[rr] * il;
      out[o + 16 + c] = acc1[rr] * il;
    }
  }
}

extern "C" void kernel_launch(void* const* d_in, const int* in_sizes, int n_in,
                              void* d_out, int out_size, void* d_ws, size_t ws_size,
                              hipStream_t stream) {
  const float* x = (const float*)d_in[0];
  const int* adj = (const int*)d_in[1];
  const float* W = (const float*)d_in[2];
  const float* a = (const float*)d_in[3];
  float* out = (float*)d_out;

  char* ws = (char*)d_ws;
  _Float16* hT = (_Float16*)ws;                              // 4 MB
  _Float16* WT = (_Float16*)(ws + (size_t)4 * 1024 * 1024);  // 128 KB
  float* s1_ws = (float*)(ws + (size_t)4 * 1024 * 1024 + 128 * 1024);
  float* s2_ws = s1_ws + (size_t)BB * H * NN;
  unsigned* adjP = (unsigned*)(s2_ws + (size_t)BB * H * NN);  // 1 MB

  prep_w<<<16, 256, 0, stream>>>(W, WT);
  gemm_pack<<<dim3(384, 4), 256, 0, stream>>>(x, WT, a, adj, adjP, hT, s1_ws, s2_ws);
  attn<<<dim3(64, 32), 256, 0, stream>>>(hT, s1_ws, s2_ws, adjP, out);
}

// Round 5
// 122.919 us; speedup vs baseline: 1.0997x; 1.0997x over previous
//
#include <hip/hip_runtime.h>
#include <math.h>

#define H 4
#define HD 64
#define NN 1024
#define BB 8
#define FIN 256
#define FOUT 256

typedef _Float16 f16x8 __attribute__((ext_vector_type(8)));
typedef _Float16 f16x4 __attribute__((ext_vector_type(4)));
typedef _Float16 f16x2 __attribute__((ext_vector_type(2)));
typedef float f32x4 __attribute__((ext_vector_type(4)));

// ---------------------------------------------------------------------------
// Kernel 0: prep. Blocks 0..1023: pack adj -> 1 bit/edge (streaming).
// Blocks 1024..1039: WT[f][k] = (fp16) W[k][f] in 64x64 tiles.
// ---------------------------------------------------------------------------
__global__ __launch_bounds__(256) void prep(const int* __restrict__ adj,
                                            unsigned* __restrict__ adjP,
                                            const float* __restrict__ W,
                                            _Float16* __restrict__ WT) {
  __shared__ float tile[64][68];
  const int tid = threadIdx.x;
  if (blockIdx.x < 1024) {
    size_t widx = (size_t)blockIdx.x * 256 + tid;  // [0, 8*1024*32)
    const int4* p = (const int4*)adj + widx * 8;
    int4 v[8];
#pragma unroll
    for (int i = 0; i < 8; ++i) v[i] = p[i];
    unsigned bits = 0;
#pragma unroll
    for (int i = 0; i < 8; ++i) {
      bits |= (v[i].x != 0 ? 1u : 0u) << (4 * i);
      bits |= (v[i].y != 0 ? 2u : 0u) << (4 * i);
      bits |= (v[i].z != 0 ? 4u : 0u) << (4 * i);
      bits |= (v[i].w != 0 ? 8u : 0u) << (4 * i);
    }
    adjP[widx] = bits;
  } else {
    const int bx = blockIdx.x - 1024;
    const int k0 = (bx & 3) * 64, f0 = (bx >> 2) * 64;
    const int r = tid >> 4, c4 = (tid & 15) * 4;
#pragma unroll
    for (int p = 0; p < 4; ++p) {
      float4 v = *(const float4*)&W[(size_t)(k0 + p * 16 + r) * FOUT + f0 + c4];
      *(float4*)&tile[p * 16 + r][c4] = v;
    }
    __syncthreads();
    const int f = tid >> 2, kg = (tid & 3) * 16;
#pragma unroll
    for (int i = 0; i < 4; ++i) {
      f16x4 o;
#pragma unroll
      for (int j = 0; j < 4; ++j) o[j] = (_Float16)tile[kg + i * 4 + j][f];
      *(f16x4*)&WT[(size_t)(f0 + f) * FIN + k0 + kg + i * 4] = o;
    }
  }
}

// ---------------------------------------------------------------------------
// Kernel 1: h = x @ W via fp16 MFMA. Block = 64 rows x 1 head, 512 blocks.
// Two-phase x staging (16 float4 in flight); W B-frags from WT (L2 b128s).
// Epilogue fuses scores: s1, s2, u=exp(s2), v=exp(0.2*s2).
// ---------------------------------------------------------------------------
__global__ __launch_bounds__(256) void gemm_xw(const float* __restrict__ x,
                                               const _Float16* __restrict__ WT,
                                               const float* __restrict__ a,
                                               _Float16* __restrict__ hT,
                                               float* __restrict__ s1_ws,
                                               float* __restrict__ s2_ws,
                                               float* __restrict__ u_ws,
                                               float* __restrict__ v_ws) {
  __shared__ _Float16 xs[64][264];  // stride 528B
  const int tid = threadIdx.x;
  const int lane = tid & 63, w = tid >> 6;
  const int c = lane & 15, q = lane >> 4;
  const int bn0 = blockIdx.x * 64;
  const int head = blockIdx.y;
  const int b = bn0 >> 10, nb = bn0 & 1023;
  const int bh = b * H + head;

  float4 v[16];
#pragma unroll
  for (int p = 0; p < 16; ++p) {
    int f = p * 256 + tid;  // float4 index in [0, 4096)
    int row = f >> 6, col = (f & 63) * 4;
    v[p] = *(const float4*)&x[(size_t)(bn0 + row) * FIN + col];
  }
#pragma unroll
  for (int p = 0; p < 16; ++p) {
    int f = p * 256 + tid;
    int row = f >> 6, col = (f & 63) * 4;
    f16x4 h4;
    h4[0] = (_Float16)v[p].x; h4[1] = (_Float16)v[p].y;
    h4[2] = (_Float16)v[p].z; h4[3] = (_Float16)v[p].w;
    *(f16x4*)&xs[row][col] = h4;
  }
  __syncthreads();

  f32x4 acc[4];
#pragma unroll
  for (int t = 0; t < 4; ++t) acc[t] = (f32x4){0.f, 0.f, 0.f, 0.f};
  const _Float16* wbase = WT + (size_t)head * 64 * FIN;
#pragma unroll
  for (int ks = 0; ks < 8; ++ks) {
    f16x8 af = *(const f16x8*)&xs[w * 16 + c][ks * 32 + q * 8];
#pragma unroll
    for (int t = 0; t < 4; ++t) {
      f16x8 bf = *(const f16x8*)&wbase[(size_t)(t * 16 + c) * FIN + ks * 32 + q * 8];
      acc[t] = __builtin_amdgcn_mfma_f32_16x16x32_f16(af, bf, acc[t], 0, 0, 0);
    }
  }

  float a1v[4], a2v[4];
#pragma unroll
  for (int t = 0; t < 4; ++t) {
    a1v[t] = a[head * 2 * HD + t * 16 + c];
    a2v[t] = a[head * 2 * HD + HD + t * 16 + c];
  }
  float s1p[4] = {0.f, 0.f, 0.f, 0.f};
  float s2p[4] = {0.f, 0.f, 0.f, 0.f};
#pragma unroll
  for (int t = 0; t < 4; ++t) {
    f16x4 hv;
#pragma unroll
    for (int rr = 0; rr < 4; ++rr) {
      hv[rr] = (_Float16)acc[t][rr];
      s1p[rr] += acc[t][rr] * a1v[t];
      s2p[rr] += acc[t][rr] * a2v[t];
    }
    *(f16x4*)&hT[((size_t)(bh * 64 + t * 16 + c)) * NN + nb + w * 16 + q * 4] = hv;
  }
#pragma unroll
  for (int rr = 0; rr < 4; ++rr) {
    float s1 = s1p[rr], s2 = s2p[rr];
#pragma unroll
    for (int off = 8; off; off >>= 1) {
      s1 += __shfl_xor(s1, off);
      s2 += __shfl_xor(s2, off);
    }
    if (c == 0) {
      int n = nb + w * 16 + q * 4 + rr;
      size_t idx = (size_t)bh * NN + n;
      s1_ws[idx] = s1;
      s2_ws[idx] = s2;
      u_ws[idx] = __expf(s2);
      v_ws[idx] = __expf(0.2f * s2);
    }
  }
}

// ---------------------------------------------------------------------------
// Kernel 2: attention. Block = 32 n-rows x (b,h); 1024 blocks, 4 waves.
// Identical to the 118.8us baseline EXCEPT:
//  (a) P-gen of chunk ch+1 is moved INSIDE chunk ch's MFMA phase (between the
//      A-frag ds_reads and the MFMAs), writing the OTHER pt buffer — hazard-
//      free via the existing double buffer; the ~250cy of P-gen VALU now
//      hides LDS read + B-frag global prefetch latency instead of sitting
//      serially before each barrier.
//  (b) XCD-aware (ntile,bh) swizzle: all 32 ntiles of one bh (sharing the same
//      hT slice / score rows / adjP rows) land on one XCD's L2.
// ---------------------------------------------------------------------------
__global__ __launch_bounds__(256) void attn(const _Float16* __restrict__ hT,
                                            const float* __restrict__ s1_ws,
                                            const float* __restrict__ s2_ws,
                                            const float* __restrict__ u_ws,
                                            const float* __restrict__ v_ws,
                                            const unsigned* __restrict__ adjP,
                                            float* __restrict__ out) {
  __shared__ float s2r[NN], uu[NN], vv[NN];  // 12 KB
  __shared__ _Float16 pt[2][32][136];        // 17 KB
  __shared__ unsigned adjW[32][32];          // 4 KB packed mask
  __shared__ float invL[32];
  const int tid = threadIdx.x, lane = tid & 63, w = tid >> 6;
  const int c = lane & 15, q = lane >> 4;
  const int bid = blockIdx.y * 32 + blockIdx.x;
  const int work = ((bid & 7) << 7) | (bid >> 3);  // XCD swizzle (1024%8==0)
  const int ntile = work & 31, bh = work >> 5;
  const int b = bh >> 2, head = bh & 3;
  const int n0 = ntile * 32;

  {
    size_t base = (size_t)bh * NN + tid * 4;
    *(float4*)&s2r[tid * 4] = *(const float4*)&s2_ws[base];
    *(float4*)&uu[tid * 4] = *(const float4*)&u_ws[base];
    *(float4*)&vv[tid * 4] = *(const float4*)&v_ws[base];
    uint4 aw = *(const uint4*)&adjP[((size_t)(b * NN + n0)) * 32 + tid * 4];
    *(uint4*)&adjW[tid >> 3][(tid * 4) & 31] = aw;
  }
  __syncthreads();

  float s1v[8];
#pragma unroll
  for (int r = 0; r < 8; ++r) s1v[r] = s1_ws[(size_t)bh * NN + n0 + w * 8 + r];

  const int wc = lane >> 4;          // word within the 128-m chunk
  const int shft = (2 * lane) & 31;  // bit position of m = 2*lane

  // ---- pass 1: masked max of s2 per row (mask bits from LDS) ----
  float mx[8];
#pragma unroll
  for (int r = 0; r < 8; ++r) mx[r] = -INFINITY;
#pragma unroll
  for (int ch = 0; ch < 8; ++ch) {
    float2 s2p = *(const float2*)&s2r[ch * 128 + 2 * lane];
#pragma unroll
    for (int r = 0; r < 8; ++r) {
      unsigned bits = adjW[w * 8 + r][ch * 4 + wc] >> shft;
      mx[r] = fmaxf(mx[r], (bits & 1u) ? s2p.x : -INFINITY);
      mx[r] = fmaxf(mx[r], (bits & 2u) ? s2p.y : -INFINITY);
    }
  }
  float Arow[8], Brow[8], ns1[8];
#pragma unroll
  for (int r = 0; r < 8; ++r) {
    float m = mx[r];
#pragma unroll
    for (int off = 32; off; off >>= 1) m = fmaxf(m, __shfl_xor(m, off));
    float t0 = s1v[r] + m;
    float M = fmaxf(t0, 0.2f * t0);  // lrelu (monotone => exact row max)
    Arow[r] = __expf(s1v[r] - M);
    Brow[r] = __expf(0.2f * s1v[r] - M);
    ns1[r] = -s1v[r];
  }

  // ---- pass 2: P-gen pipelined across the barrier ----
  float Lp[8];
#pragma unroll
  for (int r = 0; r < 8; ++r) Lp[r] = 0.f;
  f32x4 acc[2];
  acc[0] = (f32x4){0.f, 0.f, 0.f, 0.f};
  acc[1] = (f32x4){0.f, 0.f, 0.f, 0.f};
  const _Float16* bptr = hT + ((size_t)bh * 64 + w * 16 + c) * NN + q * 8;

  auto PGEN = [&](int ch, int buf) {
    float2 s2p = *(const float2*)&s2r[ch * 128 + 2 * lane];
    float2 up = *(const float2*)&uu[ch * 128 + 2 * lane];
    float2 vp = *(const float2*)&vv[ch * 128 + 2 * lane];
#pragma unroll
    for (int r = 0; r < 8; ++r) {
      unsigned bits = adjW[w * 8 + r][ch * 4 + wc] >> shft;
      float p0 = (s2p.x >= ns1[r]) ? Arow[r] * up.x : Brow[r] * vp.x;
      float p1 = (s2p.y >= ns1[r]) ? Arow[r] * up.y : Brow[r] * vp.y;
      p0 = (bits & 1u) ? p0 : 0.f;
      p1 = (bits & 2u) ? p1 : 0.f;
      Lp[r] += p0 + p1;
      f16x2 pk = __builtin_bit_cast(f16x2, __builtin_amdgcn_cvt_pkrtz(p0, p1));
      *(f16x2*)&pt[buf][w * 8 + r][2 * lane] = pk;
    }
  };

  // prefetch chunk 0 B-frags + generate chunk 0 P tile
  f16x8 nbf0 = *(const f16x8*)(bptr);
  f16x8 nbf1 = *(const f16x8*)(bptr + 32);
  f16x8 nbf2 = *(const f16x8*)(bptr + 64);
  f16x8 nbf3 = *(const f16x8*)(bptr + 96);
  PGEN(0, 0);
  __syncthreads();

  for (int ch = 0; ch < 8; ++ch) {
    const int buf = ch & 1;
    f16x8 bf0 = nbf0, bf1 = nbf1, bf2 = nbf2, bf3 = nbf3;
    if (ch < 7) {  // issue next chunk's B-frags early (latency under P-gen)
      nbf0 = *(const f16x8*)(bptr + (ch + 1) * 128);
      nbf1 = *(const f16x8*)(bptr + (ch + 1) * 128 + 32);
      nbf2 = *(const f16x8*)(bptr + (ch + 1) * 128 + 64);
      nbf3 = *(const f16x8*)(bptr + (ch + 1) * 128 + 96);
    }
#pragma unroll
    for (int t = 0; t < 2; ++t) {
      f16x8 a0 = *(const f16x8*)&pt[buf][t * 16 + c][q * 8];
      f16x8 a1 = *(const f16x8*)&pt[buf][t * 16 + c][32 + q * 8];
      f16x8 a2 = *(const f16x8*)&pt[buf][t * 16 + c][64 + q * 8];
      f16x8 a3 = *(const f16x8*)&pt[buf][t * 16 + c][96 + q * 8];
      if (t == 0 && ch < 7) PGEN(ch + 1, buf ^ 1);  // hazard-free: other buffer
      acc[t] = __builtin_amdgcn_mfma_f32_16x16x32_f16(a0, bf0, acc[t], 0, 0, 0);
      acc[t] = __builtin_amdgcn_mfma_f32_16x16x32_f16(a1, bf1, acc[t], 0, 0, 0);
      acc[t] = __builtin_amdgcn_mfma_f32_16x16x32_f16(a2, bf2, acc[t], 0, 0, 0);
      acc[t] = __builtin_amdgcn_mfma_f32_16x16x32_f16(a3, bf3, acc[t], 0, 0, 0);
    }
    __syncthreads();
  }

  // ---- epilogue ----
  float myL = 0.f;
#pragma unroll
  for (int r = 0; r < 8; ++r) {
    float s = Lp[r];
#pragma unroll
    for (int off = 32; off; off >>= 1) s += __shfl_xor(s, off);
    if (lane == r) myL = s;
  }
  if (lane < 8) invL[w * 8 + lane] = 1.0f / myL;
  __syncthreads();
#pragma unroll
  for (int t = 0; t < 2; ++t) {
#pragma unroll
    for (int rr = 0; rr < 4; ++rr) {
      int nloc = t * 16 + q * 4 + rr;
      out[((size_t)(b * NN + n0 + nloc)) * FOUT + head * 64 + w * 16 + c] =
          acc[t][rr] * invL[nloc];
    }
  }
}

extern "C" void kernel_launch(void* const* d_in, const int* in_sizes, int n_in,
                              void* d_out, int out_size, void* d_ws, size_t ws_size,
                              hipStream_t stream) {
  const float* x = (const float*)d_in[0];
  const int* adj = (const int*)d_in[1];
  const float* W = (const float*)d_in[2];
  const float* a = (const float*)d_in[3];
  float* out = (float*)d_out;

  char* ws = (char*)d_ws;
  _Float16* hT = (_Float16*)ws;                              // 4 MB
  _Float16* WT = (_Float16*)(ws + (size_t)4 * 1024 * 1024);  // 128 KB
  float* s1_ws = (float*)(ws + (size_t)4 * 1024 * 1024 + 128 * 1024);
  float* s2_ws = s1_ws + (size_t)BB * H * NN;
  float* u_ws = s2_ws + (size_t)BB * H * NN;
  float* v_ws = u_ws + (size_t)BB * H * NN;
  unsigned* adjP = (unsigned*)(v_ws + (size_t)BB * H * NN);  // 1 MB

  prep<<<1040, 256, 0, stream>>>(adj, adjP, W, WT);
  gemm_xw<<<dim3(128, 4), 256, 0, stream>>>(x, WT, a, hT, s1_ws, s2_ws, u_ws, v_ws);
  attn<<<dim3(32, 32), 256, 0, stream>>>(hT, s1_ws, s2_ws, u_ws, v_ws, adjP, out);
}

// Round 6
// 116.800 us; speedup vs baseline: 1.1573x; 1.0524x over previous
//
#include <hip/hip_runtime.h>
#include <math.h>

#define H 4
#define HD 64
#define NN 1024
#define BB 8
#define FIN 256
#define FOUT 256

typedef _Float16 f16x8 __attribute__((ext_vector_type(8)));
typedef _Float16 f16x4 __attribute__((ext_vector_type(4)));
typedef _Float16 f16x2 __attribute__((ext_vector_type(2)));
typedef float f32x4 __attribute__((ext_vector_type(4)));

// ---------------------------------------------------------------------------
// Kernel 0: prep. Blocks 0..1023: pack adj -> 1 bit/edge (streaming).
// Blocks 1024..1039: WT[f][k] = (fp16) W[k][f] in 64x64 tiles.
// ---------------------------------------------------------------------------
__global__ __launch_bounds__(256) void prep(const int* __restrict__ adj,
                                            unsigned* __restrict__ adjP,
                                            const float* __restrict__ W,
                                            _Float16* __restrict__ WT) {
  __shared__ float tile[64][68];
  const int tid = threadIdx.x;
  if (blockIdx.x < 1024) {
    size_t widx = (size_t)blockIdx.x * 256 + tid;  // [0, 8*1024*32)
    const int4* p = (const int4*)adj + widx * 8;
    int4 v[8];
#pragma unroll
    for (int i = 0; i < 8; ++i) v[i] = p[i];
    unsigned bits = 0;
#pragma unroll
    for (int i = 0; i < 8; ++i) {
      bits |= (v[i].x != 0 ? 1u : 0u) << (4 * i);
      bits |= (v[i].y != 0 ? 2u : 0u) << (4 * i);
      bits |= (v[i].z != 0 ? 4u : 0u) << (4 * i);
      bits |= (v[i].w != 0 ? 8u : 0u) << (4 * i);
    }
    adjP[widx] = bits;
  } else {
    const int bx = blockIdx.x - 1024;
    const int k0 = (bx & 3) * 64, f0 = (bx >> 2) * 64;
    const int r = tid >> 4, c4 = (tid & 15) * 4;
#pragma unroll
    for (int p = 0; p < 4; ++p) {
      float4 v = *(const float4*)&W[(size_t)(k0 + p * 16 + r) * FOUT + f0 + c4];
      *(float4*)&tile[p * 16 + r][c4] = v;
    }
    __syncthreads();
    const int f = tid >> 2, kg = (tid & 3) * 16;
#pragma unroll
    for (int i = 0; i < 4; ++i) {
      f16x4 o;
#pragma unroll
      for (int j = 0; j < 4; ++j) o[j] = (_Float16)tile[kg + i * 4 + j][f];
      *(f16x4*)&WT[(size_t)(f0 + f) * FIN + k0 + kg + i * 4] = o;
    }
  }
}

// ---------------------------------------------------------------------------
// Kernel 1: h = x @ W via fp16 MFMA. Block = 64 rows x 1 head, 512 blocks.
// Two-phase x staging (16 float4 in flight); W B-frags from WT (L2 b128s).
// Epilogue fuses scores: s1, s2, u=exp(s2), v=exp(0.2*s2).
// ---------------------------------------------------------------------------
__global__ __launch_bounds__(256) void gemm_xw(const float* __restrict__ x,
                                               const _Float16* __restrict__ WT,
                                               const float* __restrict__ a,
                                               _Float16* __restrict__ hT,
                                               float* __restrict__ s1_ws,
                                               float* __restrict__ s2_ws,
                                               float* __restrict__ u_ws,
                                               float* __restrict__ v_ws) {
  __shared__ _Float16 xs[64][264];  // stride 528B
  const int tid = threadIdx.x;
  const int lane = tid & 63, w = tid >> 6;
  const int c = lane & 15, q = lane >> 4;
  const int bn0 = blockIdx.x * 64;
  const int head = blockIdx.y;
  const int b = bn0 >> 10, nb = bn0 & 1023;
  const int bh = b * H + head;

  float4 v[16];
#pragma unroll
  for (int p = 0; p < 16; ++p) {
    int f = p * 256 + tid;  // float4 index in [0, 4096)
    int row = f >> 6, col = (f & 63) * 4;
    v[p] = *(const float4*)&x[(size_t)(bn0 + row) * FIN + col];
  }
#pragma unroll
  for (int p = 0; p < 16; ++p) {
    int f = p * 256 + tid;
    int row = f >> 6, col = (f & 63) * 4;
    f16x4 h4;
    h4[0] = (_Float16)v[p].x; h4[1] = (_Float16)v[p].y;
    h4[2] = (_Float16)v[p].z; h4[3] = (_Float16)v[p].w;
    *(f16x4*)&xs[row][col] = h4;
  }
  __syncthreads();

  f32x4 acc[4];
#pragma unroll
  for (int t = 0; t < 4; ++t) acc[t] = (f32x4){0.f, 0.f, 0.f, 0.f};
  const _Float16* wbase = WT + (size_t)head * 64 * FIN;
#pragma unroll
  for (int ks = 0; ks < 8; ++ks) {
    f16x8 af = *(const f16x8*)&xs[w * 16 + c][ks * 32 + q * 8];
#pragma unroll
    for (int t = 0; t < 4; ++t) {
      f16x8 bf = *(const f16x8*)&wbase[(size_t)(t * 16 + c) * FIN + ks * 32 + q * 8];
      acc[t] = __builtin_amdgcn_mfma_f32_16x16x32_f16(af, bf, acc[t], 0, 0, 0);
    }
  }

  float a1v[4], a2v[4];
#pragma unroll
  for (int t = 0; t < 4; ++t) {
    a1v[t] = a[head * 2 * HD + t * 16 + c];
    a2v[t] = a[head * 2 * HD + HD + t * 16 + c];
  }
  float s1p[4] = {0.f, 0.f, 0.f, 0.f};
  float s2p[4] = {0.f, 0.f, 0.f, 0.f};
#pragma unroll
  for (int t = 0; t < 4; ++t) {
    f16x4 hv;
#pragma unroll
    for (int rr = 0; rr < 4; ++rr) {
      hv[rr] = (_Float16)acc[t][rr];
      s1p[rr] += acc[t][rr] * a1v[t];
      s2p[rr] += acc[t][rr] * a2v[t];
    }
    *(f16x4*)&hT[((size_t)(bh * 64 + t * 16 + c)) * NN + nb + w * 16 + q * 4] = hv;
  }
#pragma unroll
  for (int rr = 0; rr < 4; ++rr) {
    float s1 = s1p[rr], s2 = s2p[rr];
#pragma unroll
    for (int off = 8; off; off >>= 1) {
      s1 += __shfl_xor(s1, off);
      s2 += __shfl_xor(s2, off);
    }
    if (c == 0) {
      int n = nb + w * 16 + q * 4 + rr;
      size_t idx = (size_t)bh * NN + n;
      s1_ws[idx] = s1;
      s2_ws[idx] = s2;
      u_ws[idx] = __expf(s2);
      v_ws[idx] = __expf(0.2f * s2);
    }
  }
}

// ---------------------------------------------------------------------------
// Kernel 2: attention. Block = 32 n-rows x (b,h); 1024 blocks, 4 waves.
// NO pt LDS tile, NO main-loop barriers: wave w owns k-quarter [256w,256w+256).
// Lane (c,q) computes its own MFMA A-fragments in registers — rows {c,c+16},
// k = ks*32+q*8..+7 — from per-row constants + broadcast s2/u/v LDS reads +
// one adj byte (transposed adjT, broadcast). acc[2][4] = 8 independent MFMA
// chains. Cross-wave k-reduction: 2-round LDS butterfly. 5 barriers total.
// ---------------------------------------------------------------------------
__global__ __launch_bounds__(256) void attn(const _Float16* __restrict__ hT,
                                            const float* __restrict__ s1_ws,
                                            const float* __restrict__ s2_ws,
                                            const float* __restrict__ u_ws,
                                            const float* __restrict__ v_ws,
                                            const unsigned* __restrict__ adjP,
                                            float* __restrict__ out) {
  __shared__ float s2r[NN], uu[NN], vv[NN];   // 12 KB
  __shared__ unsigned adjT[32][32];           // 4 KB, [word][row]
  __shared__ float accbuf[2][2][4][64][4];    // 16 KB reduction buffer
  __shared__ float Mbuf[4][32];               // 512 B
  __shared__ float Lbuf[4][32];               // 512 B
  __shared__ float invLb[32];                 // 128 B
  const int tid = threadIdx.x, lane = tid & 63, w = tid >> 6;
  const int c = lane & 15, q = lane >> 4;
  const int ntile = blockIdx.x, bh = blockIdx.y;
  const int b = bh >> 2, head = bh & 3;
  const int n0 = ntile * 32;
  const int K0 = w * 256, W0 = w * 8;  // this wave's k-quarter

  {
    size_t base = (size_t)bh * NN + tid * 4;
    *(float4*)&s2r[tid * 4] = *(const float4*)&s2_ws[base];
    *(float4*)&uu[tid * 4] = *(const float4*)&u_ws[base];
    *(float4*)&vv[tid * 4] = *(const float4*)&v_ws[base];
    const int row = tid >> 3, wd0 = (tid & 7) * 4;
    uint4 aw = *(const uint4*)&adjP[((size_t)(b * NN + n0 + row)) * 32 + wd0];
    adjT[wd0 + 0][row] = aw.x;
    adjT[wd0 + 1][row] = aw.y;
    adjT[wd0 + 2][row] = aw.z;
    adjT[wd0 + 3][row] = aw.w;
  }
  float s1A = s1_ws[(size_t)bh * NN + n0 + c];       // row c
  float s1B = s1_ws[(size_t)bh * NN + n0 + 16 + c];  // row c+16
  __syncthreads();

  // ---- pass 1: masked max of s2 over this wave's k-quarter, rows c & c+16 --
  float mxA = -INFINITY, mxB = -INFINITY;
#pragma unroll
  for (int ks = 0; ks < 8; ++ks) {
    int m0 = K0 + ks * 32 + q * 8;
    f32x4 sa = *(const f32x4*)&s2r[m0];
    f32x4 sb = *(const f32x4*)&s2r[m0 + 4];
    unsigned wdA = adjT[W0 + ks][c] >> (q * 8);
    unsigned wdB = adjT[W0 + ks][c + 16] >> (q * 8);
#pragma unroll
    for (int j = 0; j < 4; ++j) {
      mxA = fmaxf(mxA, ((wdA >> j) & 1u) ? sa[j] : -INFINITY);
      mxA = fmaxf(mxA, ((wdA >> (j + 4)) & 1u) ? sb[j] : -INFINITY);
      mxB = fmaxf(mxB, ((wdB >> j) & 1u) ? sa[j] : -INFINITY);
      mxB = fmaxf(mxB, ((wdB >> (j + 4)) & 1u) ? sb[j] : -INFINITY);
    }
  }
  mxA = fmaxf(mxA, __shfl_xor(mxA, 16));
  mxA = fmaxf(mxA, __shfl_xor(mxA, 32));
  mxB = fmaxf(mxB, __shfl_xor(mxB, 16));
  mxB = fmaxf(mxB, __shfl_xor(mxB, 32));
  if (lane < 16) {
    Mbuf[w][c] = mxA;
    Mbuf[w][16 + c] = mxB;
  }
  __syncthreads();
  float mrowA = fmaxf(fmaxf(Mbuf[0][c], Mbuf[1][c]), fmaxf(Mbuf[2][c], Mbuf[3][c]));
  float mrowB = fmaxf(fmaxf(Mbuf[0][16 + c], Mbuf[1][16 + c]),
                      fmaxf(Mbuf[2][16 + c], Mbuf[3][16 + c]));
  float tA = s1A + mrowA, tB = s1B + mrowB;
  float MA = fmaxf(tA, 0.2f * tA);  // lrelu (monotone => exact row max)
  float MB = fmaxf(tB, 0.2f * tB);
  float ArowA = __expf(s1A - MA), BrowA = __expf(0.2f * s1A - MA), ns1A = -s1A;
  float ArowB = __expf(s1B - MB), BrowB = __expf(0.2f * s1B - MB), ns1B = -s1B;

  // ---- pass 2: barrier-free main loop over this wave's k-quarter ----
  float LpA = 0.f, LpB = 0.f;
  f32x4 acc[2][4];
#pragma unroll
  for (int t = 0; t < 2; ++t)
#pragma unroll
    for (int d = 0; d < 4; ++d) acc[t][d] = (f32x4){0.f, 0.f, 0.f, 0.f};
  const _Float16* hbase = hT + (size_t)bh * 64 * NN + (size_t)c * NN + K0 + q * 8;

#pragma unroll 2
  for (int ks = 0; ks < 8; ++ks) {
    // B-frags for this k-slice, all 4 d-blocks (issued before A-build -> the
    // ~160cy of P-gen VALU below hides the L2 latency)
    f16x8 bf0 = *(const f16x8*)(hbase + (size_t)0 * 16 * NN + ks * 32);
    f16x8 bf1 = *(const f16x8*)(hbase + (size_t)1 * 16 * NN + ks * 32);
    f16x8 bf2 = *(const f16x8*)(hbase + (size_t)2 * 16 * NN + ks * 32);
    f16x8 bf3 = *(const f16x8*)(hbase + (size_t)3 * 16 * NN + ks * 32);

    int m0 = K0 + ks * 32 + q * 8;
    f32x4 sa = *(const f32x4*)&s2r[m0];
    f32x4 sb = *(const f32x4*)&s2r[m0 + 4];
    f32x4 ua = *(const f32x4*)&uu[m0];
    f32x4 ub = *(const f32x4*)&uu[m0 + 4];
    f32x4 va = *(const f32x4*)&vv[m0];
    f32x4 vb = *(const f32x4*)&vv[m0 + 4];
    unsigned wdA = adjT[W0 + ks][c] >> (q * 8);
    unsigned wdB = adjT[W0 + ks][c + 16] >> (q * 8);

    float pA[8], pB[8];
#pragma unroll
    for (int j = 0; j < 4; ++j) {
      float a0 = (sa[j] >= ns1A) ? ArowA * ua[j] : BrowA * va[j];
      float a1 = (sb[j] >= ns1A) ? ArowA * ub[j] : BrowA * vb[j];
      pA[j] = ((wdA >> j) & 1u) ? a0 : 0.f;
      pA[j + 4] = ((wdA >> (j + 4)) & 1u) ? a1 : 0.f;
      float b0 = (sa[j] >= ns1B) ? ArowB * ua[j] : BrowB * va[j];
      float b1 = (sb[j] >= ns1B) ? ArowB * ub[j] : BrowB * vb[j];
      pB[j] = ((wdB >> j) & 1u) ? b0 : 0.f;
      pB[j + 4] = ((wdB >> (j + 4)) & 1u) ? b1 : 0.f;
    }
    LpA += ((pA[0] + pA[1]) + (pA[2] + pA[3])) + ((pA[4] + pA[5]) + (pA[6] + pA[7]));
    LpB += ((pB[0] + pB[1]) + (pB[2] + pB[3])) + ((pB[4] + pB[5]) + (pB[6] + pB[7]));

    union { f16x8 v8; f16x2 h2[4]; } PA, PB;
#pragma unroll
    for (int j = 0; j < 4; ++j) {
      PA.h2[j] = __builtin_bit_cast(f16x2, __builtin_amdgcn_cvt_pkrtz(pA[2 * j], pA[2 * j + 1]));
      PB.h2[j] = __builtin_bit_cast(f16x2, __builtin_amdgcn_cvt_pkrtz(pB[2 * j], pB[2 * j + 1]));
    }

    acc[0][0] = __builtin_amdgcn_mfma_f32_16x16x32_f16(PA.v8, bf0, acc[0][0], 0, 0, 0);
    acc[0][1] = __builtin_amdgcn_mfma_f32_16x16x32_f16(PA.v8, bf1, acc[0][1], 0, 0, 0);
    acc[0][2] = __builtin_amdgcn_mfma_f32_16x16x32_f16(PA.v8, bf2, acc[0][2], 0, 0, 0);
    acc[0][3] = __builtin_amdgcn_mfma_f32_16x16x32_f16(PA.v8, bf3, acc[0][3], 0, 0, 0);
    acc[1][0] = __builtin_amdgcn_mfma_f32_16x16x32_f16(PB.v8, bf0, acc[1][0], 0, 0, 0);
    acc[1][1] = __builtin_amdgcn_mfma_f32_16x16x32_f16(PB.v8, bf1, acc[1][1], 0, 0, 0);
    acc[1][2] = __builtin_amdgcn_mfma_f32_16x16x32_f16(PB.v8, bf2, acc[1][2], 0, 0, 0);
    acc[1][3] = __builtin_amdgcn_mfma_f32_16x16x32_f16(PB.v8, bf3, acc[1][3], 0, 0, 0);
  }

  // ---- epilogue: L + acc cross-wave k-reduction (2-round butterfly) ----
  LpA += __shfl_xor(LpA, 16);
  LpA += __shfl_xor(LpA, 32);
  LpB += __shfl_xor(LpB, 16);
  LpB += __shfl_xor(LpB, 32);
  if (lane < 16) {
    Lbuf[w][c] = LpA;
    Lbuf[w][16 + c] = LpB;
  }
  if (w >= 2) {  // round 1: waves 2,3 publish
#pragma unroll
    for (int t = 0; t < 2; ++t)
#pragma unroll
      for (int d = 0; d < 4; ++d)
        *(f32x4*)&accbuf[w - 2][t][d][lane][0] = acc[t][d];
  }
  __syncthreads();
  if (w < 2) {
#pragma unroll
    for (int t = 0; t < 2; ++t)
#pragma unroll
      for (int d = 0; d < 4; ++d)
        acc[t][d] += *(const f32x4*)&accbuf[w][t][d][lane][0];
  }
  if (tid < 32) {
    float Ls = Lbuf[0][tid] + Lbuf[1][tid] + Lbuf[2][tid] + Lbuf[3][tid];
    invLb[tid] = 1.0f / Ls;
  }
  __syncthreads();
  if (w == 1) {  // round 2: wave 1 publishes
#pragma unroll
    for (int t = 0; t < 2; ++t)
#pragma unroll
      for (int d = 0; d < 4; ++d)
        *(f32x4*)&accbuf[0][t][d][lane][0] = acc[t][d];
  }
  __syncthreads();
  if (w == 0) {
#pragma unroll
    for (int t = 0; t < 2; ++t) {
#pragma unroll
      for (int d = 0; d < 4; ++d)
        acc[t][d] += *(const f32x4*)&accbuf[0][t][d][lane][0];
#pragma unroll
      for (int rr = 0; rr < 4; ++rr) {
        int nloc = t * 16 + q * 4 + rr;
        float il = invLb[nloc];
        size_t o = ((size_t)(b * NN + n0 + nloc)) * FOUT + head * 64;
#pragma unroll
        for (int d = 0; d < 4; ++d) out[o + d * 16 + c] = acc[t][d][rr] * il;
      }
    }
  }
}

extern "C" void kernel_launch(void* const* d_in, const int* in_sizes, int n_in,
                              void* d_out, int out_size, void* d_ws, size_t ws_size,
                              hipStream_t stream) {
  const float* x = (const float*)d_in[0];
  const int* adj = (const int*)d_in[1];
  const float* W = (const float*)d_in[2];
  const float* a = (const float*)d_in[3];
  float* out = (float*)d_out;

  char* ws = (char*)d_ws;
  _Float16* hT = (_Float16*)ws;                              // 4 MB
  _Float16* WT = (_Float16*)(ws + (size_t)4 * 1024 * 1024);  // 128 KB
  float* s1_ws = (float*)(ws + (size_t)4 * 1024 * 1024 + 128 * 1024);
  float* s2_ws = s1_ws + (size_t)BB * H * NN;
  float* u_ws = s2_ws + (size_t)BB * H * NN;
  float* v_ws = u_ws + (size_t)BB * H * NN;
  unsigned* adjP = (unsigned*)(v_ws + (size_t)BB * H * NN);  // 1 MB

  prep<<<1040, 256, 0, stream>>>(adj, adjP, W, WT);
  gemm_xw<<<dim3(128, 4), 256, 0, stream>>>(x, WT, a, hT, s1_ws, s2_ws, u_ws, v_ws);
  attn<<<dim3(32, 32), 256, 0, stream>>>(hT, s1_ws, s2_ws, u_ws, v_ws, adjP, out);
}